// Round 7
// baseline (58.437 us; speedup 1.0000x reference)
//
#include <hip/hip_runtime.h>

constexpr int NIMG    = 32;
constexpr int W       = 512;
constexpr int S       = 16;                     // row-slices per image
constexpr int ROWS    = W / S;                  // 32 rows per slice
constexpr int HW_C    = 32896;                  // compact triangle cells = 256*257/2
constexpr int WORDS_C = HW_C / 2;               // 16448 u32 (64.25 KB LDS)
constexpr int U4_C    = WORDS_C / 4;            // 4112 uint4 per slice histogram
constexpr int K2C     = 16;                     // phase-2 chunks per image
constexpr int U4_PC   = U4_C / K2C;             // 257 uint4 per chunk
constexpr float SUMQ  = 2.0f * 511.0f * 512.0f; // sum of symmetrized histogram

// ---------------------------------------------------------------------------
// canonical triangle insert: pair (a,b) -> cell (d=|a-b|, i=min(a,b))
// halfword addr h = d*(513-d)/2 + i ; ONE atomic per pair.
// u16 safety: slice has 32*511 = 16352 pairs < 65536 -> cannot overflow.
// ---------------------------------------------------------------------------
__device__ __forceinline__ void tri_add(unsigned int* sh, int a, int b) {
    int d = (a > b) ? (a - b) : (b - a);
    int m = (a < b) ? a : b;
    int h = (__mul24(d, 513 - d) >> 1) + m;     // d<256 -> mul24 exact, full-rate
    atomicAdd(&sh[h >> 1], 1u << ((h & 1) << 4));
}

__device__ __forceinline__ int quant(float v) {
    int q = (int)(v * 256.0f);                  // trunc toward zero == astype(int32)
    return min(255, max(0, q));
}

__device__ __forceinline__ float wave_red(float v) {
#pragma unroll
    for (int off = 32; off; off >>= 1) v += __shfl_down(v, off);
    return v;
}

// ---------------------------------------------------------------------------
// K1: one block per (image, slice). Slice triangle histogram in 64.25 KB LDS
// (2 blocks/CU -> 32 waves/CU), write to exclusive global region.
// ---------------------------------------------------------------------------
__global__ void __launch_bounds__(1024)
glcm_hist(const float* __restrict__ x, uint4* __restrict__ hist) {
    __shared__ unsigned int sh[WORDS_C];
    const int t    = threadIdx.x;
    const int bid  = blockIdx.x;
    const int lane = t & 63;

    uint4* sh4 = reinterpret_cast<uint4*>(sh);
    for (int g = t; g < U4_C; g += 1024) sh4[g] = uint4{0u, 0u, 0u, 0u};
    __syncthreads();

    const float* __restrict__ xb = x + (size_t)bid * ROWS * W;
    const int nf4 = ROWS * (W / 4);             // 4096 float4s -> 4 iters/thread

    for (int f = t; f < nf4; f += 1024) {
        float4 v = reinterpret_cast<const float4*>(xb)[f];
        int b0 = quant(v.x);
        int b1 = quant(v.y);
        int b2 = quant(v.z);
        int b3 = quant(v.w);
        int nb0 = __shfl_down(b0, 1);           // lane l+1's b0 == my b4
        tri_add(sh, b0, b1);
        tri_add(sh, b1, b2);
        tri_add(sh, b2, b3);
        if ((f & (W / 4 - 1)) != (W / 4 - 1)) { // not last float4 of its row
            int b4 = (lane == 63) ? quant(xb[f * 4 + 4]) : nb0;
            tri_add(sh, b3, b4);
        }
    }
    __syncthreads();

    uint4* __restrict__ hb = hist + (size_t)bid * U4_C;
    for (int g = t; g < U4_C; g += 1024) hb[g] = sh4[g];
}

// ---------------------------------------------------------------------------
// K2: grid = NIMG*K2C blocks. Block (img,chunk) sums its 257-uint4 range
// across the image's 16 slice histograms, recovers (d,i), accumulates the 7
// feature sums, block-reduces, publishes partials (agent-scope stores); the
// last arriver per image (atomic ticket, residue check -> no reset needed)
// sums partials in fixed order (bit-deterministic) and emits the features.
//
// Cell (d,i), j=i+d, count c. Full-matrix identities:
//   contrast = 2*sum c*d^2 ; dissim = 2*sum c*d ; homog = 2*sum c/(1+d^2)
//   sum Q*i = sum c*(i+j) ; sum Q*i^2 = sum c*(i^2+j^2) ; sum Q*ij = 2*sum c*i*j
//   sum Q^2 = 2*sum w*c^2, w=2 on diagonal (d==0) else 1
// ---------------------------------------------------------------------------
__global__ void __launch_bounds__(256)
glcm_feat(const uint4* __restrict__ hist, float* __restrict__ part,
          unsigned int* __restrict__ tickets, float* __restrict__ out) {
    const int img   = blockIdx.x >> 4;
    const int chunk = blockIdx.x & 15;
    const uint4* __restrict__ hb = hist + (size_t)img * S * U4_C;

    float s_con = 0.f, s_dis = 0.f, s_hom = 0.f;
    float s_i = 0.f, s_ii = 0.f, s_ij = 0.f, s_q2 = 0.f;

    for (int g = threadIdx.x; g < U4_PC; g += 256) {
        const int g_abs = chunk * U4_PC + g;

        unsigned int c0 = 0, c1 = 0, c2 = 0, c3 = 0, c4 = 0, c5 = 0, c6 = 0, c7 = 0;
#pragma unroll
        for (int s = 0; s < S; ++s) {
            uint4 v = hb[(size_t)s * U4_C + g_abs];
            c0 += v.x & 0xFFFFu;  c1 += v.x >> 16;
            c2 += v.y & 0xFFFFu;  c3 += v.y >> 16;
            c4 += v.z & 0xFFFFu;  c5 += v.z >> 16;
            c6 += v.w & 0xFFFFu;  c7 += v.w >> 16;
        }
        unsigned int cc[8] = {c0, c1, c2, c3, c4, c5, c6, c7};

        // invert h0 = 8*g_abs -> (d,i):  off(d) = d*(513-d)/2 <= h0 < off(d+1)
        const int h0 = g_abs << 3;
        int d = (int)((513.0f - sqrtf((float)(263169 - 8 * h0))) * 0.5f);
        while ((d * (513 - d)) / 2 > h0) --d;               // exact fixup
        while (((d + 1) * (512 - d)) / 2 <= h0) ++d;
        int i = h0 - (d * (513 - d)) / 2;

        const float wq = (g_abs < 32) ? 2.0f : 1.0f;        // diagonal groups
#pragma unroll
        for (int k = 0; k < 8; ++k) {
            float fc = (float)cc[k];
            float fd = (float)d;
            float fi = (float)i;
            float fj = fi + fd;
            s_con += fc * fd * fd;
            s_dis += fc * fd;
            s_hom += fc / (1.0f + fd * fd);
            s_i   += fc * (fi + fj);
            s_ii  += fc * (fi * fi + fj * fj);
            s_ij  += fc * fi * fj;
            s_q2  += wq * fc * fc;
            if (++i == 256 - d) { ++d; i = 0; }             // next diagonal
        }
    }

    float vals[7] = {s_con, s_dis, s_hom, s_i, s_ii, s_ij, s_q2};
    __shared__ float red[4][7];
    const int lane = threadIdx.x & 63;
    const int wv   = threadIdx.x >> 6;
#pragma unroll
    for (int q = 0; q < 7; ++q) {
        float v = wave_red(vals[q]);
        if (lane == 0) red[wv][q] = v;
    }
    __syncthreads();

    if (threadIdx.x == 0) {
        float* p = part + (size_t)(img * K2C + chunk) * 8;
#pragma unroll
        for (int q = 0; q < 7; ++q)
            __hip_atomic_store(&p[q], red[0][q] + red[1][q] + red[2][q] + red[3][q],
                               __ATOMIC_RELEASE, __HIP_MEMORY_SCOPE_AGENT);

        unsigned int prev = __hip_atomic_fetch_add(&tickets[img], 1u,
                                                   __ATOMIC_ACQ_REL,
                                                   __HIP_MEMORY_SCOPE_AGENT);
        if ((prev & 15u) == 15u) {              // last of any 16 -> no reset needed
            float m[7] = {0.f, 0.f, 0.f, 0.f, 0.f, 0.f, 0.f};
            for (int c = 0; c < K2C; ++c) {     // fixed order: deterministic
                const float* q = part + (size_t)(img * K2C + c) * 8;
#pragma unroll
                for (int k = 0; k < 7; ++k)
                    m[k] += __hip_atomic_load(&q[k], __ATOMIC_RELAXED,
                                              __HIP_MEMORY_SCOPE_AGENT);
            }
            const float inv = 1.0f / SUMQ;
            float contrast = 2.0f * m[0] * inv;
            float dissim   = 2.0f * m[1] * inv;
            float homog    = 2.0f * m[2] * inv;
            float mu       = m[3] * inv;
            float var      = m[4] * inv - mu * mu;          // var_i == var_j
            float cov      = 2.0f * m[5] * inv - mu * mu;
            float energy   = sqrtf(2.0f * m[6]) * inv;
            float corr     = (var < 1e-15f) ? 1.0f : (cov / var);

            out[img * 5 + 0] = contrast;
            out[img * 5 + 1] = dissim;
            out[img * 5 + 2] = homog;
            out[img * 5 + 3] = energy;
            out[img * 5 + 4] = corr;
        }
    }
}

extern "C" void kernel_launch(void* const* d_in, const int* in_sizes, int n_in,
                              void* d_out, int out_size, void* d_ws, size_t ws_size,
                              hipStream_t stream) {
    const float* x = (const float*)d_in[0];
    float* out = (float*)d_out;

    // ws layout: [hist: 512 * 4112 uint4 = 33.7 MB][part: 32*16*8 f32][tickets: 32 u32]
    uint4* hist = (uint4*)d_ws;
    float* part = (float*)((char*)d_ws + (size_t)NIMG * S * U4_C * sizeof(uint4));
    unsigned int* tickets = (unsigned int*)(part + (size_t)NIMG * K2C * 8);

    glcm_hist<<<NIMG * S, 1024, 0, stream>>>(x, hist);
    glcm_feat<<<NIMG * K2C, 256, 0, stream>>>(hist, part, tickets, out);
}

// Round 8
// 40.321 us; speedup vs baseline: 1.4493x; 1.4493x over previous
//
#include <hip/hip_runtime.h>

constexpr int NIMG    = 32;
constexpr int W       = 512;
constexpr int S       = 8;                      // row-slices per image
constexpr int ROWS    = W / S;                  // 64 rows per slice
constexpr int HW_C    = 32896;                  // compact triangle cells = 256*257/2
constexpr int WORDS_C = HW_C / 2;               // 16448 u32 (64.25 KB LDS)
constexpr int U4_C    = WORDS_C / 4;            // 4112 uint4 per slice histogram
constexpr int K2C     = 16;                     // energy chunks per image
constexpr int U4_PC   = U4_C / K2C;             // 257 uint4 per chunk
constexpr float SUMQ  = 2.0f * 511.0f * 512.0f; // sum of symmetrized histogram

// ---------------------------------------------------------------------------
// canonical triangle insert: pair (a,b) -> cell (d=|a-b|, i=min(a,b))
// halfword addr h = d*(513-d)/2 + i ; ONE atomic per pair.
// u16 safety: slice has 64*511 = 32704 pairs < 65536 -> cannot overflow.
// ---------------------------------------------------------------------------
__device__ __forceinline__ void tri_add(unsigned int* sh, int a, int b) {
    int d = (a > b) ? (a - b) : (b - a);
    int m = (a < b) ? a : b;
    int h = (__mul24(d, 513 - d) >> 1) + m;     // d<256 -> mul24 exact
    atomicAdd(&sh[h >> 1], 1u << ((h & 1) << 4));
}

__device__ __forceinline__ int quant(float v) {
    int q = (int)(v * 256.0f);                  // trunc toward zero == astype(int32)
    return min(255, max(0, q));
}

__device__ __forceinline__ float wave_red(float v) {
#pragma unroll
    for (int off = 32; off; off >>= 1) v += __shfl_down(v, off);
    return v;
}

// ---------------------------------------------------------------------------
// K1: one block per (image, slice). Triangle histogram in 64.25 KB LDS, then
// a single fused sweep: write slice to global AND accumulate the 6 linear
// moments (linear in Q -> per-slice partials sum exactly).
//   cell (d,i), j=i+d, count c:
//   contrast' = sum c*d^2 ; dissim' = sum c*d ; homog' = sum c/(1+d^2)
//   si' = sum c*(i+j) ; sii' = sum c*(i^2+j^2) ; sij' = sum c*i*j
// (final: contrast=2*con'/SUMQ etc., diagonal consistent — verified round 5)
// ---------------------------------------------------------------------------
__global__ void __launch_bounds__(1024)
glcm_hist(const float* __restrict__ x, uint4* __restrict__ hist,
          float* __restrict__ mom) {
    __shared__ unsigned int sh[WORDS_C];
    __shared__ float red[16][6];
    const int t    = threadIdx.x;
    const int bid  = blockIdx.x;
    const int lane = t & 63;

    uint4* sh4 = reinterpret_cast<uint4*>(sh);
    for (int g = t; g < U4_C; g += 1024) sh4[g] = uint4{0u, 0u, 0u, 0u};
    __syncthreads();

    // ---- histogram ----
    const float* __restrict__ xb = x + (size_t)bid * ROWS * W;
    const int nf4 = ROWS * (W / 4);             // 8192 float4s -> 8 iters/thread

    for (int f = t; f < nf4; f += 1024) {
        float4 v = reinterpret_cast<const float4*>(xb)[f];
        int b0 = quant(v.x);
        int b1 = quant(v.y);
        int b2 = quant(v.z);
        int b3 = quant(v.w);
        int nb0 = __shfl_down(b0, 1);           // lane l+1's b0 == my b4
        tri_add(sh, b0, b1);
        tri_add(sh, b1, b2);
        tri_add(sh, b2, b3);
        if ((f & (W / 4 - 1)) != (W / 4 - 1)) { // not last float4 of its row
            int b4 = (lane == 63) ? quant(xb[f * 4 + 4]) : nb0;
            tri_add(sh, b3, b4);
        }
    }
    __syncthreads();

    // ---- fused write-out + linear moments ----
    uint4* __restrict__ hb = hist + (size_t)bid * U4_C;
    float s_con = 0.f, s_dis = 0.f, s_hom = 0.f;
    float s_i = 0.f, s_ii = 0.f, s_ij = 0.f;

    for (int g = t; g < U4_C; g += 1024) {
        uint4 v = sh4[g];
        hb[g] = v;
        unsigned int cc[8] = {v.x & 0xFFFFu, v.x >> 16, v.y & 0xFFFFu, v.y >> 16,
                              v.z & 0xFFFFu, v.z >> 16, v.w & 0xFFFFu, v.w >> 16};
        // invert h0 = 8*g -> (d,i):  off(d) = d*(513-d)/2 <= h0 < off(d+1)
        const int h0 = g << 3;
        int d = (int)((513.0f - sqrtf((float)(263169 - 8 * h0))) * 0.5f);
        while ((d * (513 - d)) / 2 > h0) --d;   // exact fixup
        while (((d + 1) * (512 - d)) / 2 <= h0) ++d;
        int i = h0 - (d * (513 - d)) / 2;
#pragma unroll
        for (int k = 0; k < 8; ++k) {
            float fc = (float)cc[k];
            float fd = (float)d;
            float fi = (float)i;
            float fj = fi + fd;
            s_con += fc * fd * fd;
            s_dis += fc * fd;
            s_hom += fc / (1.0f + fd * fd);
            s_i   += fc * (fi + fj);
            s_ii  += fc * (fi * fi + fj * fj);
            s_ij  += fc * fi * fj;
            if (++i == 256 - d) { ++d; i = 0; } // next diagonal
        }
    }

    float vals[6] = {s_con, s_dis, s_hom, s_i, s_ii, s_ij};
    const int wv = t >> 6;
#pragma unroll
    for (int q = 0; q < 6; ++q) {
        float v = wave_red(vals[q]);
        if (lane == 0) red[wv][q] = v;
    }
    __syncthreads();
    if (t == 0) {
#pragma unroll
        for (int q = 0; q < 6; ++q) {
            float a = 0.f;
            for (int w2 = 0; w2 < 16; ++w2) a += red[w2][q];
            mom[bid * 8 + q] = a;
        }
    }
}

// ---------------------------------------------------------------------------
// K2: pure energy. Block (img,chunk) sums its 257-uint4 range across the 8
// slice histograms (integer), squares, block-reduces; last arriver per image
// (atomic ticket, residue check -> no reset needed, works for any poison
// value) sums q2 partials + K1 moment partials in FIXED order and emits the
// 5 features (bit-deterministic regardless of which block finalizes).
//   sum Q^2 = 2 * sum wq * c^2,  wq=2 on diagonal cells (groups g<32) else 1
// ---------------------------------------------------------------------------
__global__ void __launch_bounds__(256)
glcm_q2(const uint4* __restrict__ hist, const float* __restrict__ mom,
        float* __restrict__ q2part, unsigned int* __restrict__ tickets,
        float* __restrict__ out) {
    const int img   = blockIdx.x >> 4;
    const int chunk = blockIdx.x & 15;
    const uint4* __restrict__ hb = hist + (size_t)img * S * U4_C;

    float q2 = 0.f;
    for (int g = chunk * U4_PC + threadIdx.x; g < (chunk + 1) * U4_PC; g += 256) {
        unsigned int c0 = 0, c1 = 0, c2 = 0, c3 = 0, c4 = 0, c5 = 0, c6 = 0, c7 = 0;
#pragma unroll
        for (int s = 0; s < S; ++s) {
            uint4 v = hb[(size_t)s * U4_C + g];
            c0 += v.x & 0xFFFFu;  c1 += v.x >> 16;
            c2 += v.y & 0xFFFFu;  c3 += v.y >> 16;
            c4 += v.z & 0xFFFFu;  c5 += v.z >> 16;
            c6 += v.w & 0xFFFFu;  c7 += v.w >> 16;
        }
        float sq = (float)c0 * (float)c0 + (float)c1 * (float)c1
                 + (float)c2 * (float)c2 + (float)c3 * (float)c3
                 + (float)c4 * (float)c4 + (float)c5 * (float)c5
                 + (float)c6 * (float)c6 + (float)c7 * (float)c7;
        q2 += (g < 32) ? 2.0f * sq : sq;        // diagonal groups double
    }

    __shared__ float red[4];
    float v = wave_red(q2);
    if ((threadIdx.x & 63) == 0) red[threadIdx.x >> 6] = v;
    __syncthreads();

    if (threadIdx.x == 0) {
        q2part[blockIdx.x] = red[0] + red[1] + red[2] + red[3];
        __threadfence();                        // release partial
        unsigned int prev = atomicAdd(&tickets[img], 1u);
        if ((prev & 15u) == 15u) {              // last of any 16 arrivals
            __threadfence();                    // acquire partials
            float m[6] = {0.f, 0.f, 0.f, 0.f, 0.f, 0.f};
            for (int s = 0; s < S; ++s) {       // fixed order: deterministic
                const float* p = mom + (size_t)(img * S + s) * 8;
#pragma unroll
                for (int k = 0; k < 6; ++k) m[k] += p[k];
            }
            float q2s = 0.f;
            for (int c = 0; c < K2C; ++c) q2s += q2part[img * K2C + c];

            const float inv = 1.0f / SUMQ;
            float contrast = 2.0f * m[0] * inv;
            float dissim   = 2.0f * m[1] * inv;
            float homog    = 2.0f * m[2] * inv;
            float mu       = m[3] * inv;
            float var      = m[4] * inv - mu * mu;      // var_i == var_j
            float cov      = 2.0f * m[5] * inv - mu * mu;
            float energy   = sqrtf(2.0f * q2s) * inv;
            float corr     = (var < 1e-15f) ? 1.0f : (cov / var);

            out[img * 5 + 0] = contrast;
            out[img * 5 + 1] = dissim;
            out[img * 5 + 2] = homog;
            out[img * 5 + 3] = energy;
            out[img * 5 + 4] = corr;
        }
    }
}

extern "C" void kernel_launch(void* const* d_in, const int* in_sizes, int n_in,
                              void* d_out, int out_size, void* d_ws, size_t ws_size,
                              hipStream_t stream) {
    const float* x = (const float*)d_in[0];
    float* out = (float*)d_out;

    // ws: [hist: 256*4112 uint4 = 16.84 MB][mom: 256*8 f32][q2part: 512 f32][tickets: 32 u32]
    uint4* hist = (uint4*)d_ws;
    float* mom = (float*)((char*)d_ws + (size_t)NIMG * S * U4_C * sizeof(uint4));
    float* q2part = mom + (size_t)NIMG * S * 8;
    unsigned int* tickets = (unsigned int*)(q2part + NIMG * K2C);

    glcm_hist<<<NIMG * S, 1024, 0, stream>>>(x, hist, mom);
    glcm_q2<<<NIMG * K2C, 256, 0, stream>>>(hist, mom, q2part, tickets, out);
}

// Round 9
// 32.910 us; speedup vs baseline: 1.7757x; 1.2252x over previous
//
#include <hip/hip_runtime.h>

constexpr int NIMG    = 32;
constexpr int W       = 512;
constexpr int S       = 8;                      // row-slices per image
constexpr int ROWS    = W / S;                  // 64 rows per slice
constexpr int HW_C    = 32896;                  // compact triangle cells = 256*257/2
constexpr int WORDS_C = HW_C / 2;               // 16448 u32 (64.25 KB LDS)
constexpr int U4_C    = WORDS_C / 4;            // 4112 uint4 per slice histogram
constexpr int K2C     = 17;                     // chunks/image: 16 full + 1 remainder
constexpr float SUMQ  = 2.0f * 511.0f * 512.0f; // sum of symmetrized histogram

// ---------------------------------------------------------------------------
// canonical triangle insert: pair (a,b) -> cell (d=|a-b|, i=min(a,b))
// halfword addr h = d*(513-d)/2 + i ; ONE atomic per pair.
// u16 safety: slice has 64*511 = 32704 pairs < 65536 -> cannot overflow.
// ---------------------------------------------------------------------------
__device__ __forceinline__ void tri_add(unsigned int* sh, int a, int b) {
    int d = (a > b) ? (a - b) : (b - a);
    int m = (a < b) ? a : b;
    int h = (__mul24(d, 513 - d) >> 1) + m;     // d<256 -> mul24 exact
    atomicAdd(&sh[h >> 1], 1u << ((h & 1) << 4));
}

__device__ __forceinline__ int quant(float v) {
    int q = (int)(v * 256.0f);                  // trunc toward zero == astype(int32)
    return min(255, max(0, q));
}

__device__ __forceinline__ float wave_red(float v) {
#pragma unroll
    for (int off = 32; off; off >>= 1) v += __shfl_down(v, off);
    return v;
}

// ---------------------------------------------------------------------------
// K1: one block per (image, slice). PURE histogram (lean registers so the
// 64.25 KB-LDS block runs 2/CU: launch_bounds(1024,8) caps VGPR at 64).
// ---------------------------------------------------------------------------
__global__ void __launch_bounds__(1024, 8)
glcm_hist(const float* __restrict__ x, uint4* __restrict__ hist) {
    __shared__ unsigned int sh[WORDS_C];
    const int t    = threadIdx.x;
    const int bid  = blockIdx.x;
    const int lane = t & 63;

    uint4* sh4 = reinterpret_cast<uint4*>(sh);
    for (int g = t; g < U4_C; g += 1024) sh4[g] = uint4{0u, 0u, 0u, 0u};
    __syncthreads();

    const float* __restrict__ xb = x + (size_t)bid * ROWS * W;
    const int nf4 = ROWS * (W / 4);             // 8192 float4s -> 8 iters/thread

    for (int f = t; f < nf4; f += 1024) {
        float4 v = reinterpret_cast<const float4*>(xb)[f];
        int b0 = quant(v.x);
        int b1 = quant(v.y);
        int b2 = quant(v.z);
        int b3 = quant(v.w);
        int nb0 = __shfl_down(b0, 1);           // lane l+1's b0 == my b4
        tri_add(sh, b0, b1);
        tri_add(sh, b1, b2);
        tri_add(sh, b2, b3);
        if ((f & (W / 4 - 1)) != (W / 4 - 1)) { // not last float4 of its row
            int b4 = (lane == 63) ? quant(xb[f * 4 + 4]) : nb0;
            tri_add(sh, b3, b4);
        }
    }
    __syncthreads();

    uint4* __restrict__ hb = hist + (size_t)bid * U4_C;
    for (int g = t; g < U4_C; g += 1024) hb[g] = sh4[g];
}

// ---------------------------------------------------------------------------
// K2: grid = NIMG*17 blocks, 256 threads, ONE uint4-group per thread
// (maximum memory-level parallelism: 8 independent slice loads issued
// back-to-back, one wait, then compute). Block (img,chunk) covers groups
// [chunk*256, chunk*256+256) clipped to 4112. Recovers (d,i), accumulates
// the 7 feature sums, block-reduces, publishes partials; the last arriver
// per image (ticket residue mod 17 -> exactly one per 17 increments for ANY
// initial value, so no reset dispatch) sums partials in fixed order
// (bit-deterministic) and emits the 5 features.
//
// Cell (d,i), j=i+d, count c (cross-slice sum). Full-matrix identities:
//   contrast = 2*sum c*d^2 ; dissim = 2*sum c*d ; homog = 2*sum c/(1+d^2)
//   sum Q*i = sum c*(i+j) ; sum Q*i^2 = sum c*(i^2+j^2) ; sum Q*ij = 2*sum c*i*j
//   sum Q^2 = 2*sum w*c^2, w=2 on diagonal cells (groups g<32) else 1
// ---------------------------------------------------------------------------
__global__ void __launch_bounds__(256)
glcm_feat(const uint4* __restrict__ hist, float* __restrict__ part,
          unsigned int* __restrict__ tickets, float* __restrict__ out) {
    const int img   = blockIdx.x / K2C;
    const int chunk = blockIdx.x % K2C;
    const int g     = chunk * 256 + threadIdx.x;

    float s_con = 0.f, s_dis = 0.f, s_hom = 0.f;
    float s_i = 0.f, s_ii = 0.f, s_ij = 0.f, s_q2 = 0.f;

    if (g < U4_C) {
        const uint4* __restrict__ hb = hist + (size_t)img * S * U4_C + g;
        uint4 vs[S];
#pragma unroll
        for (int s = 0; s < S; ++s) vs[s] = hb[(size_t)s * U4_C];  // 8 in flight

        unsigned int c0 = 0, c1 = 0, c2 = 0, c3 = 0, c4 = 0, c5 = 0, c6 = 0, c7 = 0;
#pragma unroll
        for (int s = 0; s < S; ++s) {
            c0 += vs[s].x & 0xFFFFu;  c1 += vs[s].x >> 16;
            c2 += vs[s].y & 0xFFFFu;  c3 += vs[s].y >> 16;
            c4 += vs[s].z & 0xFFFFu;  c5 += vs[s].z >> 16;
            c6 += vs[s].w & 0xFFFFu;  c7 += vs[s].w >> 16;
        }
        unsigned int cc[8] = {c0, c1, c2, c3, c4, c5, c6, c7};

        // invert h0 = 8*g -> (d,i):  off(d) = d*(513-d)/2 <= h0 < off(d+1)
        const int h0 = g << 3;
        int d = (int)((513.0f - sqrtf((float)(263169 - 8 * h0))) * 0.5f);
        while ((d * (513 - d)) / 2 > h0) --d;               // exact fixup
        while (((d + 1) * (512 - d)) / 2 <= h0) ++d;
        int i = h0 - (d * (513 - d)) / 2;

        const float wq = (g < 32) ? 2.0f : 1.0f;            // diagonal groups
#pragma unroll
        for (int k = 0; k < 8; ++k) {
            float fc = (float)cc[k];
            float fd = (float)d;
            float fi = (float)i;
            float fj = fi + fd;
            s_con += fc * fd * fd;
            s_dis += fc * fd;
            s_hom += fc / (1.0f + fd * fd);
            s_i   += fc * (fi + fj);
            s_ii  += fc * (fi * fi + fj * fj);
            s_ij  += fc * fi * fj;
            s_q2  += wq * fc * fc;
            if (++i == 256 - d) { ++d; i = 0; }             // next diagonal
        }
    }

    float vals[7] = {s_con, s_dis, s_hom, s_i, s_ii, s_ij, s_q2};
    __shared__ float red[4][7];
    const int lane = threadIdx.x & 63;
    const int wv   = threadIdx.x >> 6;
#pragma unroll
    for (int q = 0; q < 7; ++q) {
        float v = wave_red(vals[q]);
        if (lane == 0) red[wv][q] = v;
    }
    __syncthreads();

    if (threadIdx.x == 0) {
        float* p = part + (size_t)(img * K2C + chunk) * 8;
#pragma unroll
        for (int q = 0; q < 7; ++q)
            p[q] = red[0][q] + red[1][q] + red[2][q] + red[3][q];

        __threadfence();                        // release partials
        unsigned int prev = atomicAdd(&tickets[img], 1u);
        if (prev % (unsigned)K2C == (unsigned)(K2C - 1)) {  // last of any 17
            __threadfence();                    // acquire partials
            float m[7] = {0.f, 0.f, 0.f, 0.f, 0.f, 0.f, 0.f};
            for (int c = 0; c < K2C; ++c) {     // fixed order: deterministic
                const float* q = part + (size_t)(img * K2C + c) * 8;
#pragma unroll
                for (int k = 0; k < 7; ++k) m[k] += q[k];
            }
            const float inv = 1.0f / SUMQ;
            float contrast = 2.0f * m[0] * inv;
            float dissim   = 2.0f * m[1] * inv;
            float homog    = 2.0f * m[2] * inv;
            float mu       = m[3] * inv;
            float var      = m[4] * inv - mu * mu;          // var_i == var_j
            float cov      = 2.0f * m[5] * inv - mu * mu;
            float energy   = sqrtf(2.0f * m[6]) * inv;
            float corr     = (var < 1e-15f) ? 1.0f : (cov / var);

            out[img * 5 + 0] = contrast;
            out[img * 5 + 1] = dissim;
            out[img * 5 + 2] = homog;
            out[img * 5 + 3] = energy;
            out[img * 5 + 4] = corr;
        }
    }
}

extern "C" void kernel_launch(void* const* d_in, const int* in_sizes, int n_in,
                              void* d_out, int out_size, void* d_ws, size_t ws_size,
                              hipStream_t stream) {
    const float* x = (const float*)d_in[0];
    float* out = (float*)d_out;

    // ws: [hist: 256*4112 uint4 = 16.84 MB][part: 32*17*8 f32][tickets: 32 u32]
    uint4* hist = (uint4*)d_ws;
    float* part = (float*)((char*)d_ws + (size_t)NIMG * S * U4_C * sizeof(uint4));
    unsigned int* tickets = (unsigned int*)(part + (size_t)NIMG * K2C * 8);

    glcm_hist<<<NIMG * S, 1024, 0, stream>>>(x, hist);
    glcm_feat<<<NIMG * K2C, 256, 0, stream>>>(hist, part, tickets, out);
}